// Round 1
// baseline (1156.418 us; speedup 1.0000x reference)
//
#include <hip/hip_runtime.h>
#include <stdint.h>

#define NN 50000
#define NE 400000
#define MPAD 50048          // 391 * 128
#define NF 500
#define KP 512

typedef __bf16 bf16;
typedef __bf16 bf16x8 __attribute__((ext_vector_type(8)));
typedef float  f32x4  __attribute__((ext_vector_type(4)));

__device__ __forceinline__ void gload16(const void* g, void* l) {
  __builtin_amdgcn_global_load_lds(
      (__attribute__((address_space(1))) void*)g,
      (__attribute__((address_space(3))) void*)l, 16, 0, 0);
}

__device__ __forceinline__ uint32_t packbf2(float a, float b) {
  union { bf16 h[2]; uint32_t u; } c;
  c.h[0] = (bf16)a; c.h[1] = (bf16)b;
  return c.u;
}

// ---------------- converts ----------------
__global__ void k_conv_x(const float* __restrict__ x, bf16* __restrict__ xbf) {
  int idx = blockIdx.x * 256 + threadIdx.x;
  if (idx >= NN * KP) return;
  int n = idx >> 9, c = idx & (KP - 1);
  float v = (c < NF) ? x[n * NF + c] : 0.f;
  xbf[idx] = (bf16)v;
}

// Wa [4][500][128] -> WaT [4][128][512] (transposed, K zero-padded)
__global__ void k_conv_waT(const float* __restrict__ Wa, bf16* __restrict__ WaT) {
  int idx = blockIdx.x * 256 + threadIdx.x;
  if (idx >= 4 * 128 * KP) return;
  int b = idx >> 16;
  int r = idx & 65535;
  int n = r >> 9, k = r & 511;
  float v = (k < NF) ? Wa[(b * NF + k) * 128 + n] : 0.f;
  WaT[idx] = (bf16)v;
}

// W [batch][K][N] -> WT [batch][N][K]
__global__ void k_conv_wT(const float* __restrict__ W, bf16* __restrict__ WT, int Kd, int Nd) {
  int idx = blockIdx.x * 256 + threadIdx.x;
  int tot = Kd * Nd;
  if (idx >= tot) return;
  int n = idx / Kd, k = idx - n * Kd;
  WT[(size_t)blockIdx.y * tot + idx] = (bf16)W[(size_t)blockIdx.y * tot + k * Nd + n];
}

// ---------------- CSR build (counting sort by dst) ----------------
__global__ void k_hist(const int* __restrict__ dst, int* __restrict__ counts) {
  int idx = blockIdx.x * 256 + threadIdx.x;
  if (idx >= 4 * NE) return;
  int b = idx / NE;
  atomicAdd(&counts[b * NN + dst[idx]], 1);
}

__global__ void __launch_bounds__(1024) k_scan(const int* __restrict__ counts, int* __restrict__ offs) {
  constexpr int CH = (NN + 1023) / 1024;
  int b = blockIdx.x;
  const int* c = counts + b * NN;
  int* o = offs + b * (NN + 1);
  __shared__ int part[1024];
  int t = threadIdx.x;
  int beg = t * CH, end = min(beg + CH, NN);
  int s = 0;
  for (int i = beg; i < end; ++i) s += c[i];
  part[t] = s;
  __syncthreads();
  for (int d = 1; d < 1024; d <<= 1) {
    int v = (t >= d) ? part[t - d] : 0;
    __syncthreads();
    part[t] += v;
    __syncthreads();
  }
  int run = t ? part[t - 1] : 0;
  for (int i = beg; i < end; ++i) { o[i] = run; run += c[i]; }
  if (t == 1023) o[NN] = part[1023];
}

__global__ void k_scatter(const int* __restrict__ src, const int* __restrict__ dst,
                          const float* __restrict__ val, const int* __restrict__ offs,
                          int* __restrict__ fill, int* __restrict__ csrc, float* __restrict__ cval) {
  int idx = blockIdx.x * 256 + threadIdx.x;
  if (idx >= 4 * NE) return;
  int b = idx / NE;
  int d = dst[idx];
  int pos = offs[b * (NN + 1) + d] + atomicAdd(&fill[b * NN + d], 1);
  csrc[b * NE + pos] = src[idx];
  cval[b * NE + pos] = val[idx];
}

// ---------------- SpMM (pull mode over CSR) ----------------
// out[b*outBr + n*ldOut + f] = relu?( sum_e val*sup[b][src][f] + bias[b*DIM+f] )
template <int DIM>
__global__ void __launch_bounds__(256) k_spmm(
    const bf16* __restrict__ sup, const int* __restrict__ offs,
    const int* __restrict__ csrc, const float* __restrict__ cval,
    const float* __restrict__ bias, bf16* __restrict__ out,
    int ldOut, long long outBr, int relu) {
  constexpr int TPN = DIM / 2;
  constexpr int NPB = 256 / TPN;
  int b = blockIdx.z;
  int lt = threadIdx.x & (TPN - 1);
  int n = blockIdx.x * NPB + threadIdx.x / TPN;
  if (n >= NN) return;
  const int* o = offs + b * (NN + 1);
  int e0 = o[n], e1 = o[n + 1];
  const bf16* supb = sup + (size_t)b * MPAD * DIM;
  const int* sb = csrc + (size_t)b * NE;
  const float* vb = cval + (size_t)b * NE;
  float a0 = 0.f, a1 = 0.f;
  for (int e = e0; e < e1; ++e) {
    int s = sb[e];
    float v = vb[e];
    union { uint32_t u; bf16 h[2]; } cv;
    cv.u = *(const uint32_t*)(supb + (size_t)s * DIM + lt * 2);
    a0 = fmaf(v, (float)cv.h[0], a0);
    a1 = fmaf(v, (float)cv.h[1], a1);
  }
  a0 += bias[b * DIM + lt * 2];
  a1 += bias[b * DIM + lt * 2 + 1];
  if (relu) { a0 = fmaxf(a0, 0.f); a1 = fmaxf(a1, 0.f); }
  *(uint32_t*)(out + (size_t)b * outBr + (size_t)n * ldOut + lt * 2) = packbf2(a0, a1);
}

// ---------------- bf16 MFMA GEMM ----------------
// C[MPAD][ldC](bf16) = A[MPAD][ldA](bf16) @ B^T[BN][K](bf16), single N-tile (N==BN)
// optional fused bias+relu. Batched via blockIdx.z with element strides sA/sB/sC.
template <int BN, bool BR>
__global__ void __launch_bounds__(256) k_gemm(
    const bf16* __restrict__ A, const bf16* __restrict__ B, bf16* __restrict__ C,
    const float* __restrict__ bias, int K, int ldA, int ldC,
    size_t sA, size_t sB, size_t sC) {
  constexpr int WN = BN / 2;
  constexpr int NFR = WN / 16;
  constexpr int BL = BN / 32;                 // B-stage loads per wave
  __shared__ __align__(16) unsigned char sa[128 * 128];   // 128 rows x 128B (64 bf16)
  __shared__ __align__(16) unsigned char sb[BN * 128];
  int tid = threadIdx.x;
  int lane = tid & 63;
  int wid = tid >> 6;
  int wm = wid & 1, wn = wid >> 1;
  const bf16* Ab = A + sA * blockIdx.z;
  const bf16* Bb = B + sB * blockIdx.z;
  bf16* Cb = C + sC * blockIdx.z;
  int gm0 = blockIdx.x * 128;

  f32x4 acc[4][NFR];
#pragma unroll
  for (int i = 0; i < 4; ++i)
#pragma unroll
    for (int j = 0; j < NFR; ++j) acc[i][j] = (f32x4){0.f, 0.f, 0.f, 0.f};

  for (int kt = 0; kt < K; kt += 64) {
    // stage A tile [128][64] with XOR swizzle applied on the GLOBAL source side
#pragma unroll
    for (int i = 0; i < 4; ++i) {
      int lb = (wid * 4 + i) * 1024 + lane * 16;
      int r = lb >> 7;
      int c = (lb >> 4) & 7;
      gload16(Ab + (size_t)(gm0 + r) * ldA + kt + ((c ^ (r & 7)) << 3),
              &sa[(wid * 4 + i) * 1024]);
    }
#pragma unroll
    for (int i = 0; i < BL; ++i) {
      int lb = (wid * BL + i) * 1024 + lane * 16;
      int r = lb >> 7;
      int c = (lb >> 4) & 7;
      gload16(Bb + (size_t)r * K + kt + ((c ^ (r & 7)) << 3),
              &sb[(wid * BL + i) * 1024]);
    }
    __syncthreads();
#pragma unroll
    for (int kk = 0; kk < 2; ++kk) {
      bf16x8 ar[4], br[NFR];
#pragma unroll
      for (int mi = 0; mi < 4; ++mi) {
        int r = wm * 64 + mi * 16 + (lane & 15);
        int c = (kk * 4 + (lane >> 4)) ^ (r & 7);
        ar[mi] = *(const bf16x8*)&sa[r * 128 + c * 16];
      }
#pragma unroll
      for (int ni = 0; ni < NFR; ++ni) {
        int r = wn * WN + ni * 16 + (lane & 15);
        int c = (kk * 4 + (lane >> 4)) ^ (r & 7);
        br[ni] = *(const bf16x8*)&sb[r * 128 + c * 16];
      }
      // swapped operands: lane holds m=l&15 (row), 4 consecutive n per acc reg
#pragma unroll
      for (int mi = 0; mi < 4; ++mi)
#pragma unroll
        for (int ni = 0; ni < NFR; ++ni)
          acc[mi][ni] = __builtin_amdgcn_mfma_f32_16x16x32_bf16(br[ni], ar[mi], acc[mi][ni], 0, 0, 0);
    }
    __syncthreads();
  }

#pragma unroll
  for (int mi = 0; mi < 4; ++mi) {
    int m = gm0 + wm * 64 + mi * 16 + (lane & 15);
#pragma unroll
    for (int ni = 0; ni < NFR; ++ni) {
      int n0 = wn * WN + ni * 16 + ((lane >> 4) << 2);
      f32x4 v = acc[mi][ni];
      if (BR) {
        const f32x4 bv = *(const f32x4*)&bias[n0];
        v[0] = fmaxf(v[0] + bv[0], 0.f);
        v[1] = fmaxf(v[1] + bv[1], 0.f);
        v[2] = fmaxf(v[2] + bv[2], 0.f);
        v[3] = fmaxf(v[3] + bv[3], 0.f);
      }
      uint2 st;
      st.x = packbf2(v[0], v[1]);
      st.y = packbf2(v[2], v[3]);
      *(uint2*)(Cb + (size_t)m * ldC + n0) = st;
    }
  }
}

// ---------------- dense heads: out[n][c] = sum_d relu(X[n][d]) * W[d][c] + bias[c] ----------------
__global__ void k_head(const bf16* __restrict__ X, int ldX,
                       const float* __restrict__ W, const float* __restrict__ bias,
                       float* __restrict__ out) {
  int idx = blockIdx.x * 256 + threadIdx.x;
  if (idx >= NN * 40) return;
  int n = idx / 40, c = idx - n * 40;
  const bf16* xr = X + (size_t)n * ldX;
  float acc = bias[c];
#pragma unroll
  for (int d2 = 0; d2 < 32; ++d2) {
    union { uint32_t u; bf16 h[2]; } cv;
    cv.u = *(const uint32_t*)(xr + d2 * 2);
    acc = fmaf(fmaxf((float)cv.h[0], 0.f), W[(d2 * 2) * 40 + c], acc);
    acc = fmaf(fmaxf((float)cv.h[1], 0.f), W[(d2 * 2 + 1) * 40 + c], acc);
  }
  out[idx] = acc;
}

extern "C" void kernel_launch(void* const* d_in, const int* in_sizes, int n_in,
                              void* d_out, int out_size, void* d_ws, size_t ws_size,
                              hipStream_t stream) {
  (void)in_sizes; (void)n_in; (void)out_size; (void)ws_size;
  const float* x   = (const float*)d_in[0];
  const int*   src = (const int*)d_in[1];
  const int*   dst = (const int*)d_in[2];
  const float* val = (const float*)d_in[3];
  const float* Wa  = (const float*)d_in[4];
  const float* ba  = (const float*)d_in[5];
  const float* Wb  = (const float*)d_in[6];
  const float* bb  = (const float*)d_in[7];
  const float* Wc  = (const float*)d_in[8];
  const float* bc  = (const float*)d_in[9];
  const float* dW  = (const float*)d_in[10];
  const float* db  = (const float*)d_in[11];
  const float* e1W = (const float*)d_in[12];
  const float* e1b = (const float*)d_in[13];
  const float* e2W = (const float*)d_in[14];
  const float* e2b = (const float*)d_in[15];
  const float* e3W = (const float*)d_in[16];
  const float* e3b = (const float*)d_in[17];
  float* out = (float*)d_out;

  uint8_t* ws = (uint8_t*)d_ws;
  size_t off = 0;
  auto carve = [&](size_t sz) -> void* {
    void* p = ws + off;
    off = (off + sz + 255) & ~(size_t)255;
    return p;
  };

  bf16* xbf   = (bf16*)carve((size_t)MPAD * KP * 2);       // 51.2 MB (aliased later by e-bufs)
  bf16* WaT   = (bf16*)carve((size_t)4 * 128 * KP * 2);
  bf16* WbT   = (bf16*)carve((size_t)4 * 128 * 128 * 2);
  bf16* WcT   = (bf16*)carve((size_t)4 * 64 * 128 * 2);
  bf16* e1WT  = (bf16*)carve((size_t)128 * 256 * 2);
  bf16* e2WT  = (bf16*)carve((size_t)128 * 128 * 2);
  bf16* e3WT  = (bf16*)carve((size_t)64 * 128 * 2);
  bf16* bufS  = (bf16*)carve((size_t)4 * MPAD * 128 * 2);  // support1/2/3
  bf16* bufH  = (bf16*)carve((size_t)4 * MPAD * 128 * 2);  // h1/h2, then xbcat [MPAD][256]
  int*  counts= (int*)carve((size_t)4 * NN * 4);           // must stay adjacent to fill
  int*  fill  = (int*)carve((size_t)4 * NN * 4);
  int*  offs  = (int*)carve((size_t)4 * (NN + 1) * 4);
  int*  csrc  = (int*)carve((size_t)4 * NE * 4);
  float* cval = (float*)carve((size_t)4 * NE * 4);
  // e-bufs alias xbf (dead after GEMM1)
  bf16* e1buf = xbf;
  bf16* e2buf = xbf + (size_t)MPAD * 128;
  bf16* e3buf = xbf + (size_t)2 * MPAD * 128;

  // zero counts+fill (contiguous, 800000 bytes each, 256-aligned exactly)
  hipMemsetAsync(counts, 0, (size_t)2 * 4 * NN * 4, stream);

  // converts
  k_conv_x  <<<(NN * KP + 255) / 256, 256, 0, stream>>>(x, xbf);
  k_conv_waT<<<(4 * 128 * KP + 255) / 256, 256, 0, stream>>>(Wa, WaT);
  k_conv_wT <<<dim3((128 * 128 + 255) / 256, 4), 256, 0, stream>>>(Wb, WbT, 128, 128);
  k_conv_wT <<<dim3((128 * 64 + 255) / 256, 4), 256, 0, stream>>>(Wc, WcT, 128, 64);
  k_conv_wT <<<dim3((256 * 128 + 255) / 256, 1), 256, 0, stream>>>(e1W, e1WT, 256, 128);
  k_conv_wT <<<dim3((128 * 128 + 255) / 256, 1), 256, 0, stream>>>(e2W, e2WT, 128, 128);
  k_conv_wT <<<dim3((128 * 64 + 255) / 256, 1), 256, 0, stream>>>(e3W, e3WT, 128, 64);

  // CSR build
  k_hist   <<<(4 * NE + 255) / 256, 256, 0, stream>>>(dst, counts);
  k_scan   <<<4, 1024, 0, stream>>>(counts, offs);
  k_scatter<<<(4 * NE + 255) / 256, 256, 0, stream>>>(src, dst, val, offs, fill, csrc, cval);

  const dim3 gemmGrid4(MPAD / 128, 1, 4);
  const dim3 gemmGrid1(MPAD / 128, 1, 1);

  // layer 1: support1 = xbf @ WaT^T ; h1 = relu(spmm + ba)
  k_gemm<128, false><<<gemmGrid4, 256, 0, stream>>>(xbf, WaT, bufS, nullptr, KP, KP, 128,
                                                    0, (size_t)128 * KP, (size_t)MPAD * 128);
  k_spmm<128><<<dim3((NN + 3) / 4, 1, 4), 256, 0, stream>>>(bufS, offs, csrc, cval, ba, bufH,
                                                            128, (long long)MPAD * 128, 1);
  // layer 2
  k_gemm<128, false><<<gemmGrid4, 256, 0, stream>>>(bufH, WbT, bufS, nullptr, 128, 128, 128,
                                                    (size_t)MPAD * 128, (size_t)128 * 128, (size_t)MPAD * 128);
  k_spmm<128><<<dim3((NN + 3) / 4, 1, 4), 256, 0, stream>>>(bufS, offs, csrc, cval, bb, bufH,
                                                            128, (long long)MPAD * 128, 1);
  // layer 3 (no relu); spmm3 writes cat layout [n][branch*64+d] into bufH
  k_gemm<64, false><<<gemmGrid4, 256, 0, stream>>>(bufH, WcT, bufS, nullptr, 128, 128, 64,
                                                   (size_t)MPAD * 128, (size_t)64 * 128, (size_t)MPAD * 64);
  k_spmm<64><<<dim3((NN + 7) / 8, 1, 4), 256, 0, stream>>>(bufS, offs, csrc, cval, bc, bufH,
                                                           256, 64, 0);
  // per-branch dense heads on relu(xb)
  for (int k = 0; k < 4; ++k)
    k_head<<<(NN * 40 + 255) / 256, 256, 0, stream>>>(bufH + k * 64, 256,
                                                      dW + (size_t)k * 64 * 40, db + k * 40,
                                                      out + (size_t)k * NN * 40);
  // ensemble MLP on cat (bufH)
  k_gemm<128, true><<<gemmGrid1, 256, 0, stream>>>(bufH, e1WT, e1buf, e1b, 256, 256, 128, 0, 0, 0);
  k_gemm<128, true><<<gemmGrid1, 256, 0, stream>>>(e1buf, e2WT, e2buf, e2b, 128, 128, 128, 0, 0, 0);
  k_gemm<64,  true><<<gemmGrid1, 256, 0, stream>>>(e2buf, e3WT, e3buf, e3b, 128, 128, 64, 0, 0, 0);
  k_head<<<(NN * 40 + 255) / 256, 256, 0, stream>>>(e3buf, 64, dW + (size_t)4 * 64 * 40, db + 4 * 40,
                                                    out + (size_t)4 * NN * 40);
}

// Round 3
// 956.729 us; speedup vs baseline: 1.2087x; 1.2087x over previous
//
#include <hip/hip_runtime.h>
#include <stdint.h>

#define NN 50000
#define NE 400000
#define MPAD 50048          // 391 * 128
#define NF 500
#define KP 512

typedef __bf16 bf16;
typedef __bf16 bf16x8 __attribute__((ext_vector_type(8)));
typedef float  f32x4  __attribute__((ext_vector_type(4)));

__device__ __forceinline__ void gload16(const void* g, void* l) {
  __builtin_amdgcn_global_load_lds(
      (__attribute__((address_space(1))) void*)g,
      (__attribute__((address_space(3))) void*)l, 16, 0, 0);
}

__device__ __forceinline__ uint32_t packbf2(float a, float b) {
  union { bf16 h[2]; uint32_t u; } c;
  c.h[0] = (bf16)a; c.h[1] = (bf16)b;
  return c.u;
}

// ---------------- converts ----------------
__global__ void k_conv_x(const float* __restrict__ x, bf16* __restrict__ xbf) {
  int idx = blockIdx.x * 256 + threadIdx.x;
  if (idx >= NN * KP) return;
  int n = idx >> 9, c = idx & (KP - 1);
  float v = (c < NF) ? x[n * NF + c] : 0.f;
  xbf[idx] = (bf16)v;
}

// Wa [4][500][128] -> WaT [4][128][512] (transposed, K zero-padded)
__global__ void k_conv_waT(const float* __restrict__ Wa, bf16* __restrict__ WaT) {
  int idx = blockIdx.x * 256 + threadIdx.x;
  if (idx >= 4 * 128 * KP) return;
  int b = idx >> 16;
  int r = idx & 65535;
  int n = r >> 9, k = r & 511;
  float v = (k < NF) ? Wa[(b * NF + k) * 128 + n] : 0.f;
  WaT[idx] = (bf16)v;
}

// W [batch][K][N] -> WT [batch][N][K]
__global__ void k_conv_wT(const float* __restrict__ W, bf16* __restrict__ WT, int Kd, int Nd) {
  int idx = blockIdx.x * 256 + threadIdx.x;
  int tot = Kd * Nd;
  if (idx >= tot) return;
  int n = idx / Kd, k = idx - n * Kd;
  WT[(size_t)blockIdx.y * tot + idx] = (bf16)W[(size_t)blockIdx.y * tot + k * Nd + n];
}

// ---------------- CSR build (counting sort by dst) ----------------
__global__ void k_hist(const int* __restrict__ dst, int* __restrict__ counts) {
  int idx = blockIdx.x * 256 + threadIdx.x;
  if (idx >= 4 * NE) return;
  int b = idx / NE;
  atomicAdd(&counts[b * NN + dst[idx]], 1);
}

__global__ void __launch_bounds__(1024) k_scan(const int* __restrict__ counts, int* __restrict__ offs) {
  constexpr int CH = (NN + 1023) / 1024;
  int b = blockIdx.x;
  const int* c = counts + b * NN;
  int* o = offs + b * (NN + 1);
  __shared__ int part[1024];
  int t = threadIdx.x;
  int beg = t * CH, end = min(beg + CH, NN);
  int s = 0;
  for (int i = beg; i < end; ++i) s += c[i];
  part[t] = s;
  __syncthreads();
  for (int d = 1; d < 1024; d <<= 1) {
    int v = (t >= d) ? part[t - d] : 0;
    __syncthreads();
    part[t] += v;
    __syncthreads();
  }
  int run = t ? part[t - 1] : 0;
  for (int i = beg; i < end; ++i) { o[i] = run; run += c[i]; }
  if (t == 1023) o[NN] = part[1023];
}

__global__ void k_scatter(const int* __restrict__ src, const int* __restrict__ dst,
                          const float* __restrict__ val, const int* __restrict__ offs,
                          int* __restrict__ fill, int* __restrict__ csrc, float* __restrict__ cval) {
  int idx = blockIdx.x * 256 + threadIdx.x;
  if (idx >= 4 * NE) return;
  int b = idx / NE;
  int d = dst[idx];
  int pos = offs[b * (NN + 1) + d] + atomicAdd(&fill[b * NN + d], 1);
  csrc[b * NE + pos] = src[idx];
  cval[b * NE + pos] = val[idx];
}

// ---------------- SpMM v2 (pull mode over CSR, wave-parallel edges) ----------------
// One node per WAVE. Each lane loads 16B (8 bf16); LPS = DIM/8 lanes cover one
// edge's row; SLOTS = 64/LPS edges are gathered per wave instruction. Cross-slot
// butterfly reduce at the end. 2x unroll => up to 2*SLOTS edges in flight.
template <int DIM>
__global__ void __launch_bounds__(256) k_spmm(
    const bf16* __restrict__ sup, const int* __restrict__ offs,
    const int* __restrict__ csrc, const float* __restrict__ cval,
    const float* __restrict__ bias, bf16* __restrict__ out,
    int ldOut, long long outBr, int relu) {
  constexpr int LPS = DIM / 8;      // lanes per edge slot (16B per lane)
  constexpr int SLOTS = 64 / LPS;   // edge slots per wave
  int b = blockIdx.z;
  int lane = threadIdx.x & 63;
  int slot = lane / LPS;
  int fl = lane % LPS;              // feature block: covers [fl*8, fl*8+8)
  int n = blockIdx.x * 4 + (threadIdx.x >> 6);
  if (n >= NN) return;
  const int* o = offs + b * (NN + 1);
  int e0 = o[n], e1 = o[n + 1];
  const bf16* supb = sup + (size_t)b * MPAD * DIM;
  const int* sb = csrc + (size_t)b * NE;
  const float* vb = cval + (size_t)b * NE;

  float a[8];
#pragma unroll
  for (int j = 0; j < 8; ++j) a[j] = 0.f;

  int e = e0 + slot;
  for (; e + SLOTS < e1; e += 2 * SLOTS) {
    int s0 = sb[e];
    int s1 = sb[e + SLOTS];
    float v0 = vb[e];
    float v1 = vb[e + SLOTS];
    bf16x8 r0 = *(const bf16x8*)(supb + (size_t)s0 * DIM + fl * 8);
    bf16x8 r1 = *(const bf16x8*)(supb + (size_t)s1 * DIM + fl * 8);
#pragma unroll
    for (int j = 0; j < 8; ++j) a[j] = fmaf(v0, (float)r0[j], a[j]);
#pragma unroll
    for (int j = 0; j < 8; ++j) a[j] = fmaf(v1, (float)r1[j], a[j]);
  }
  if (e < e1) {
    int s0 = sb[e];
    float v0 = vb[e];
    bf16x8 r0 = *(const bf16x8*)(supb + (size_t)s0 * DIM + fl * 8);
#pragma unroll
    for (int j = 0; j < 8; ++j) a[j] = fmaf(v0, (float)r0[j], a[j]);
  }

  // cross-slot butterfly reduce (same fl across slots)
#pragma unroll
  for (int m = LPS; m < 64; m <<= 1) {
#pragma unroll
    for (int j = 0; j < 8; ++j) a[j] += __shfl_xor(a[j], m, 64);
  }

  if (slot == 0) {
    const float* bi = bias + b * DIM + fl * 8;
#pragma unroll
    for (int j = 0; j < 8; ++j) {
      a[j] += bi[j];
      if (relu) a[j] = fmaxf(a[j], 0.f);
    }
    union { bf16 h[8]; uint4 u4; } pk;
#pragma unroll
    for (int j = 0; j < 8; ++j) pk.h[j] = (bf16)a[j];
    *(uint4*)(out + (size_t)b * outBr + (size_t)n * ldOut + fl * 8) = pk.u4;
  }
}

// ---------------- bf16 MFMA GEMM ----------------
// C[MPAD][ldC](bf16) = A[MPAD][ldA](bf16) @ B^T[BN][K](bf16), single N-tile (N==BN)
// optional fused bias+relu. Batched via blockIdx.z with element strides sA/sB/sC.
template <int BN, bool BR>
__global__ void __launch_bounds__(256) k_gemm(
    const bf16* __restrict__ A, const bf16* __restrict__ B, bf16* __restrict__ C,
    const float* __restrict__ bias, int K, int ldA, int ldC,
    size_t sA, size_t sB, size_t sC) {
  constexpr int WN = BN / 2;
  constexpr int NFR = WN / 16;
  constexpr int BL = BN / 32;                 // B-stage loads per wave
  __shared__ __align__(16) unsigned char sa[128 * 128];   // 128 rows x 128B (64 bf16)
  __shared__ __align__(16) unsigned char sb[BN * 128];
  int tid = threadIdx.x;
  int lane = tid & 63;
  int wid = tid >> 6;
  int wm = wid & 1, wn = wid >> 1;
  const bf16* Ab = A + sA * blockIdx.z;
  const bf16* Bb = B + sB * blockIdx.z;
  bf16* Cb = C + sC * blockIdx.z;
  int gm0 = blockIdx.x * 128;

  f32x4 acc[4][NFR];
#pragma unroll
  for (int i = 0; i < 4; ++i)
#pragma unroll
    for (int j = 0; j < NFR; ++j) acc[i][j] = (f32x4){0.f, 0.f, 0.f, 0.f};

  for (int kt = 0; kt < K; kt += 64) {
    // stage A tile [128][64] with XOR swizzle applied on the GLOBAL source side
#pragma unroll
    for (int i = 0; i < 4; ++i) {
      int lb = (wid * 4 + i) * 1024 + lane * 16;
      int r = lb >> 7;
      int c = (lb >> 4) & 7;
      gload16(Ab + (size_t)(gm0 + r) * ldA + kt + ((c ^ (r & 7)) << 3),
              &sa[(wid * 4 + i) * 1024]);
    }
#pragma unroll
    for (int i = 0; i < BL; ++i) {
      int lb = (wid * BL + i) * 1024 + lane * 16;
      int r = lb >> 7;
      int c = (lb >> 4) & 7;
      gload16(Bb + (size_t)r * K + kt + ((c ^ (r & 7)) << 3),
              &sb[(wid * BL + i) * 1024]);
    }
    __syncthreads();
#pragma unroll
    for (int kk = 0; kk < 2; ++kk) {
      bf16x8 ar[4], br[NFR];
#pragma unroll
      for (int mi = 0; mi < 4; ++mi) {
        int r = wm * 64 + mi * 16 + (lane & 15);
        int c = (kk * 4 + (lane >> 4)) ^ (r & 7);
        ar[mi] = *(const bf16x8*)&sa[r * 128 + c * 16];
      }
#pragma unroll
      for (int ni = 0; ni < NFR; ++ni) {
        int r = wn * WN + ni * 16 + (lane & 15);
        int c = (kk * 4 + (lane >> 4)) ^ (r & 7);
        br[ni] = *(const bf16x8*)&sb[r * 128 + c * 16];
      }
      // swapped operands: lane holds m=l&15 (row), 4 consecutive n per acc reg
#pragma unroll
      for (int mi = 0; mi < 4; ++mi)
#pragma unroll
        for (int ni = 0; ni < NFR; ++ni)
          acc[mi][ni] = __builtin_amdgcn_mfma_f32_16x16x32_bf16(br[ni], ar[mi], acc[mi][ni], 0, 0, 0);
    }
    __syncthreads();
  }

#pragma unroll
  for (int mi = 0; mi < 4; ++mi) {
    int m = gm0 + wm * 64 + mi * 16 + (lane & 15);
#pragma unroll
    for (int ni = 0; ni < NFR; ++ni) {
      int n0 = wn * WN + ni * 16 + ((lane >> 4) << 2);
      f32x4 v = acc[mi][ni];
      if (BR) {
        const f32x4 bv = *(const f32x4*)&bias[n0];
        v[0] = fmaxf(v[0] + bv[0], 0.f);
        v[1] = fmaxf(v[1] + bv[1], 0.f);
        v[2] = fmaxf(v[2] + bv[2], 0.f);
        v[3] = fmaxf(v[3] + bv[3], 0.f);
      }
      uint2 st;
      st.x = packbf2(v[0], v[1]);
      st.y = packbf2(v[2], v[3]);
      *(uint2*)(Cb + (size_t)m * ldC + n0) = st;
    }
  }
}

// ---------------- dense heads: out[n][c] = sum_d relu(X[n][d]) * W[d][c] + bias[c] ----------------
__global__ void k_head(const bf16* __restrict__ X, int ldX,
                       const float* __restrict__ W, const float* __restrict__ bias,
                       float* __restrict__ out) {
  int idx = blockIdx.x * 256 + threadIdx.x;
  if (idx >= NN * 40) return;
  int n = idx / 40, c = idx - n * 40;
  const bf16* xr = X + (size_t)n * ldX;
  float acc = bias[c];
#pragma unroll
  for (int d2 = 0; d2 < 32; ++d2) {
    union { uint32_t u; bf16 h[2]; } cv;
    cv.u = *(const uint32_t*)(xr + d2 * 2);
    acc = fmaf(fmaxf((float)cv.h[0], 0.f), W[(d2 * 2) * 40 + c], acc);
    acc = fmaf(fmaxf((float)cv.h[1], 0.f), W[(d2 * 2 + 1) * 40 + c], acc);
  }
  out[idx] = acc;
}

extern "C" void kernel_launch(void* const* d_in, const int* in_sizes, int n_in,
                              void* d_out, int out_size, void* d_ws, size_t ws_size,
                              hipStream_t stream) {
  (void)in_sizes; (void)n_in; (void)out_size; (void)ws_size;
  const float* x   = (const float*)d_in[0];
  const int*   src = (const int*)d_in[1];
  const int*   dst = (const int*)d_in[2];
  const float* val = (const float*)d_in[3];
  const float* Wa  = (const float*)d_in[4];
  const float* ba  = (const float*)d_in[5];
  const float* Wb  = (const float*)d_in[6];
  const float* bb  = (const float*)d_in[7];
  const float* Wc  = (const float*)d_in[8];
  const float* bc  = (const float*)d_in[9];
  const float* dW  = (const float*)d_in[10];
  const float* db  = (const float*)d_in[11];
  const float* e1W = (const float*)d_in[12];
  const float* e1b = (const float*)d_in[13];
  const float* e2W = (const float*)d_in[14];
  const float* e2b = (const float*)d_in[15];
  const float* e3W = (const float*)d_in[16];
  const float* e3b = (const float*)d_in[17];
  float* out = (float*)d_out;

  uint8_t* ws = (uint8_t*)d_ws;
  size_t off = 0;
  auto carve = [&](size_t sz) -> void* {
    void* p = ws + off;
    off = (off + sz + 255) & ~(size_t)255;
    return p;
  };

  bf16* xbf   = (bf16*)carve((size_t)MPAD * KP * 2);       // 51.2 MB (aliased later by e-bufs)
  bf16* WaT   = (bf16*)carve((size_t)4 * 128 * KP * 2);
  bf16* WbT   = (bf16*)carve((size_t)4 * 128 * 128 * 2);
  bf16* WcT   = (bf16*)carve((size_t)4 * 64 * 128 * 2);
  bf16* e1WT  = (bf16*)carve((size_t)128 * 256 * 2);
  bf16* e2WT  = (bf16*)carve((size_t)128 * 128 * 2);
  bf16* e3WT  = (bf16*)carve((size_t)64 * 128 * 2);
  bf16* bufS  = (bf16*)carve((size_t)4 * MPAD * 128 * 2);  // support1/2/3
  bf16* bufH  = (bf16*)carve((size_t)4 * MPAD * 128 * 2);  // h1/h2, then xbcat [MPAD][256]
  int*  counts= (int*)carve((size_t)4 * NN * 4);           // must stay adjacent to fill
  int*  fill  = (int*)carve((size_t)4 * NN * 4);
  int*  offs  = (int*)carve((size_t)4 * (NN + 1) * 4);
  int*  csrc  = (int*)carve((size_t)4 * NE * 4);
  float* cval = (float*)carve((size_t)4 * NE * 4);
  // e-bufs alias xbf (dead after GEMM1)
  bf16* e1buf = xbf;
  bf16* e2buf = xbf + (size_t)MPAD * 128;
  bf16* e3buf = xbf + (size_t)2 * MPAD * 128;

  // zero counts+fill (contiguous, 800000 bytes each, 256-aligned exactly)
  hipMemsetAsync(counts, 0, (size_t)2 * 4 * NN * 4, stream);

  // converts
  k_conv_x  <<<(NN * KP + 255) / 256, 256, 0, stream>>>(x, xbf);
  k_conv_waT<<<(4 * 128 * KP + 255) / 256, 256, 0, stream>>>(Wa, WaT);
  k_conv_wT <<<dim3((128 * 128 + 255) / 256, 4), 256, 0, stream>>>(Wb, WbT, 128, 128);
  k_conv_wT <<<dim3((128 * 64 + 255) / 256, 4), 256, 0, stream>>>(Wc, WcT, 128, 64);
  k_conv_wT <<<dim3((256 * 128 + 255) / 256, 1), 256, 0, stream>>>(e1W, e1WT, 256, 128);
  k_conv_wT <<<dim3((128 * 128 + 255) / 256, 1), 256, 0, stream>>>(e2W, e2WT, 128, 128);
  k_conv_wT <<<dim3((128 * 64 + 255) / 256, 1), 256, 0, stream>>>(e3W, e3WT, 128, 64);

  // CSR build
  k_hist   <<<(4 * NE + 255) / 256, 256, 0, stream>>>(dst, counts);
  k_scan   <<<4, 1024, 0, stream>>>(counts, offs);
  k_scatter<<<(4 * NE + 255) / 256, 256, 0, stream>>>(src, dst, val, offs, fill, csrc, cval);

  const dim3 gemmGrid4(MPAD / 128, 1, 4);
  const dim3 gemmGrid1(MPAD / 128, 1, 1);

  // layer 1: support1 = xbf @ WaT^T ; h1 = relu(spmm + ba)
  k_gemm<128, false><<<gemmGrid4, 256, 0, stream>>>(xbf, WaT, bufS, nullptr, KP, KP, 128,
                                                    0, (size_t)128 * KP, (size_t)MPAD * 128);
  k_spmm<128><<<dim3((NN + 3) / 4, 1, 4), 256, 0, stream>>>(bufS, offs, csrc, cval, ba, bufH,
                                                            128, (long long)MPAD * 128, 1);
  // layer 2
  k_gemm<128, false><<<gemmGrid4, 256, 0, stream>>>(bufH, WbT, bufS, nullptr, 128, 128, 128,
                                                    (size_t)MPAD * 128, (size_t)128 * 128, (size_t)MPAD * 128);
  k_spmm<128><<<dim3((NN + 3) / 4, 1, 4), 256, 0, stream>>>(bufS, offs, csrc, cval, bb, bufH,
                                                            128, (long long)MPAD * 128, 1);
  // layer 3 (no relu); spmm3 writes cat layout [n][branch*64+d] into bufH
  k_gemm<64, false><<<gemmGrid4, 256, 0, stream>>>(bufH, WcT, bufS, nullptr, 128, 128, 64,
                                                   (size_t)MPAD * 128, (size_t)64 * 128, (size_t)MPAD * 64);
  k_spmm<64><<<dim3((NN + 3) / 4, 1, 4), 256, 0, stream>>>(bufS, offs, csrc, cval, bc, bufH,
                                                           256, 64, 0);
  // per-branch dense heads on relu(xb)
  for (int k = 0; k < 4; ++k)
    k_head<<<(NN * 40 + 255) / 256, 256, 0, stream>>>(bufH + k * 64, 256,
                                                      dW + (size_t)k * 64 * 40, db + k * 40,
                                                      out + (size_t)k * NN * 40);
  // ensemble MLP on cat (bufH)
  k_gemm<128, true><<<gemmGrid1, 256, 0, stream>>>(bufH, e1WT, e1buf, e1b, 256, 256, 128, 0, 0, 0);
  k_gemm<128, true><<<gemmGrid1, 256, 0, stream>>>(e1buf, e2WT, e2buf, e2b, 128, 128, 128, 0, 0, 0);
  k_gemm<64,  true><<<gemmGrid1, 256, 0, stream>>>(e2buf, e3WT, e3buf, e3b, 128, 128, 64, 0, 0, 0);
  k_head<<<(NN * 40 + 255) / 256, 256, 0, stream>>>(e3buf, 64, dW + (size_t)4 * 64 * 40, db + 4 * 40,
                                                    out + (size_t)4 * NN * 40);
}

// Round 4
// 776.130 us; speedup vs baseline: 1.4900x; 1.2327x over previous
//
#include <hip/hip_runtime.h>
#include <stdint.h>

#define NN 50000
#define NE 400000
#define MPAD 50048          // 391 * 128
#define NF 500
#define KP 512
#define NBK 196             // ceil(50000/256) coarse buckets, 256 nodes each

typedef __bf16 bf16;
typedef __bf16 bf16x8 __attribute__((ext_vector_type(8)));
typedef float  f32x4  __attribute__((ext_vector_type(4)));

__device__ __forceinline__ void gload16(const void* g, void* l) {
  __builtin_amdgcn_global_load_lds(
      (__attribute__((address_space(1))) void*)g,
      (__attribute__((address_space(3))) void*)l, 16, 0, 0);
}

__device__ __forceinline__ uint32_t packbf2(float a, float b) {
  union { bf16 h[2]; uint32_t u; } c;
  c.h[0] = (bf16)a; c.h[1] = (bf16)b;
  return c.u;
}

// ---------------- converts ----------------
__global__ void k_conv_x(const float* __restrict__ x, bf16* __restrict__ xbf) {
  int idx = blockIdx.x * 256 + threadIdx.x;
  if (idx >= NN * KP) return;
  int n = idx >> 9, c = idx & (KP - 1);
  float v = (c < NF) ? x[n * NF + c] : 0.f;
  xbf[idx] = (bf16)v;
}

// Wa [4][500][128] -> WaT [4][128][512] (transposed, K zero-padded)
__global__ void k_conv_waT(const float* __restrict__ Wa, bf16* __restrict__ WaT) {
  int idx = blockIdx.x * 256 + threadIdx.x;
  if (idx >= 4 * 128 * KP) return;
  int b = idx >> 16;
  int r = idx & 65535;
  int n = r >> 9, k = r & 511;
  float v = (k < NF) ? Wa[(b * NF + k) * 128 + n] : 0.f;
  WaT[idx] = (bf16)v;
}

// W [batch][K][N] -> WT [batch][N][K]
__global__ void k_conv_wT(const float* __restrict__ W, bf16* __restrict__ WT, int Kd, int Nd) {
  int idx = blockIdx.x * 256 + threadIdx.x;
  int tot = Kd * Nd;
  if (idx >= tot) return;
  int n = idx / Kd, k = idx - n * Kd;
  WT[(size_t)blockIdx.y * tot + idx] = (bf16)W[(size_t)blockIdx.y * tot + k * Nd + n];
}

// ---------------- CSR build v2: two-level binned counting sort ----------------
// Pass 0: coarse bucket histogram (bucket = dst>>8), LDS-aggregated.
__global__ void __launch_bounds__(256) k_bhist(const int* __restrict__ dst, int* __restrict__ bcnt) {
  __shared__ int h[256];
  int t = threadIdx.x;
  int z = blockIdx.z;
  h[t] = 0;
  __syncthreads();
  int e0 = blockIdx.x * 4096;
#pragma unroll
  for (int i = 0; i < 16; ++i) {
    int e = e0 + i * 256 + t;
    if (e < NE) atomicAdd(&h[dst[z * NE + e] >> 8], 1);
  }
  __syncthreads();
  if (t < NBK && h[t] > 0) atomicAdd(&bcnt[z * NBK + t], h[t]);
}

// Pass 1: exclusive scan of bucket counts -> bases; init gfill; offs[NN]=NE.
__global__ void __launch_bounds__(256) k_bscan(const int* __restrict__ bcnt,
                                               int* __restrict__ bases, int* __restrict__ gfill,
                                               int* __restrict__ offs) {
  __shared__ int ps[256];
  int t = threadIdx.x;
  for (int z = 0; z < 4; ++z) {
    int c = (t < NBK) ? bcnt[z * NBK + t] : 0;
    ps[t] = c;
    __syncthreads();
    for (int d = 1; d < 256; d <<= 1) {
      int v = (t >= d) ? ps[t - d] : 0;
      __syncthreads();
      ps[t] += v;
      __syncthreads();
    }
    if (t < NBK) {
      int ex = ps[t] - c;
      bases[z * (NBK + 1) + t] = ex;
      gfill[z * NBK + t] = ex;
      if (t == NBK - 1) bases[z * (NBK + 1) + NBK] = ps[t];
    }
    if (t == 0) offs[z * (NN + 1) + NN] = NE;
    __syncthreads();
  }
}

// Pass 2: bin edges into bucket-contiguous staging (int4 {src, dst, valbits, 0}).
__global__ void __launch_bounds__(256) k_bin(const int* __restrict__ src, const int* __restrict__ dst,
                                             const float* __restrict__ val, int* __restrict__ gfill,
                                             int4* __restrict__ staging) {
  __shared__ int h[256];
  __shared__ int f2[256];
  __shared__ int base[256];
  int t = threadIdx.x;
  int z = blockIdx.z;
  h[t] = 0; f2[t] = 0;
  __syncthreads();
  int e0 = blockIdx.x * 4096;
  int se[16], sd[16], sv[16];
#pragma unroll
  for (int i = 0; i < 16; ++i) {
    int e = e0 + i * 256 + t;
    sd[i] = -1;
    if (e < NE) {
      sd[i] = dst[z * NE + e];
      se[i] = src[z * NE + e];
      sv[i] = ((const int*)val)[z * NE + e];
      atomicAdd(&h[sd[i] >> 8], 1);
    }
  }
  __syncthreads();
  if (t < NBK) {
    int c = h[t];
    base[t] = c ? atomicAdd(&gfill[z * NBK + t], c) : 0;
  }
  __syncthreads();
#pragma unroll
  for (int i = 0; i < 16; ++i) {
    if (sd[i] >= 0) {
      int bkt = sd[i] >> 8;
      int loc = atomicAdd(&f2[bkt], 1);
      staging[(size_t)z * NE + base[bkt] + loc] = make_int4(se[i], sd[i], sv[i], 0);
    }
  }
}

// Pass 3: per-(branch,bucket) fine counting sort (bucket region is L2-resident),
// writes offs and packed edata {src, valbits}.
__global__ void __launch_bounds__(256) k_fine(const int4* __restrict__ staging,
                                              const int* __restrict__ bases,
                                              int* __restrict__ offs, int2* __restrict__ edata) {
  __shared__ int cnts[256];
  __shared__ int ps[256];
  __shared__ int exl[256];
  __shared__ int fl[256];
  int t = threadIdx.x;
  int z = blockIdx.z;
  int bkt = blockIdx.x;
  int base = bases[z * (NBK + 1) + bkt];
  int endp = bases[z * (NBK + 1) + bkt + 1];
  cnts[t] = 0; fl[t] = 0;
  __syncthreads();
  for (int e = base + t; e < endp; e += 256) {
    int dl = staging[(size_t)z * NE + e].y & 255;
    atomicAdd(&cnts[dl], 1);
  }
  __syncthreads();
  ps[t] = cnts[t];
  __syncthreads();
  for (int d = 1; d < 256; d <<= 1) {
    int v = (t >= d) ? ps[t - d] : 0;
    __syncthreads();
    ps[t] += v;
    __syncthreads();
  }
  exl[t] = ps[t] - cnts[t];
  int node0 = bkt * 256;
  if (node0 + t < NN) offs[z * (NN + 1) + node0 + t] = base + exl[t];
  __syncthreads();
  for (int e = base + t; e < endp; e += 256) {
    int4 g = staging[(size_t)z * NE + e];
    int dl = g.y & 255;
    int r = atomicAdd(&fl[dl], 1);
    edata[(size_t)z * NE + base + exl[dl] + r] = make_int2(g.x, g.z);
  }
}

// ---------------- SpMM v2 (pull mode over CSR, wave-parallel edges) ----------------
template <int DIM>
__global__ void __launch_bounds__(256) k_spmm(
    const bf16* __restrict__ sup, const int* __restrict__ offs,
    const int2* __restrict__ edata,
    const float* __restrict__ bias, bf16* __restrict__ out,
    int ldOut, long long outBr, int relu) {
  constexpr int LPS = DIM / 8;      // lanes per edge slot (16B per lane)
  constexpr int SLOTS = 64 / LPS;   // edge slots per wave
  int b = blockIdx.z;
  int lane = threadIdx.x & 63;
  int slot = lane / LPS;
  int fl = lane % LPS;              // feature block: covers [fl*8, fl*8+8)
  int n = blockIdx.x * 4 + (threadIdx.x >> 6);
  if (n >= NN) return;
  const int* o = offs + b * (NN + 1);
  int e0 = o[n], e1 = o[n + 1];
  const bf16* supb = sup + (size_t)b * MPAD * DIM;
  const int2* eb = edata + (size_t)b * NE;

  float a[8];
#pragma unroll
  for (int j = 0; j < 8; ++j) a[j] = 0.f;

  int e = e0 + slot;
  for (; e + SLOTS < e1; e += 2 * SLOTS) {
    int2 p0 = eb[e];
    int2 p1 = eb[e + SLOTS];
    float v0 = __int_as_float(p0.y);
    float v1 = __int_as_float(p1.y);
    bf16x8 r0 = *(const bf16x8*)(supb + (size_t)p0.x * DIM + fl * 8);
    bf16x8 r1 = *(const bf16x8*)(supb + (size_t)p1.x * DIM + fl * 8);
#pragma unroll
    for (int j = 0; j < 8; ++j) a[j] = fmaf(v0, (float)r0[j], a[j]);
#pragma unroll
    for (int j = 0; j < 8; ++j) a[j] = fmaf(v1, (float)r1[j], a[j]);
  }
  if (e < e1) {
    int2 p0 = eb[e];
    float v0 = __int_as_float(p0.y);
    bf16x8 r0 = *(const bf16x8*)(supb + (size_t)p0.x * DIM + fl * 8);
#pragma unroll
    for (int j = 0; j < 8; ++j) a[j] = fmaf(v0, (float)r0[j], a[j]);
  }

  // cross-slot butterfly reduce (same fl across slots)
#pragma unroll
  for (int m = LPS; m < 64; m <<= 1) {
#pragma unroll
    for (int j = 0; j < 8; ++j) a[j] += __shfl_xor(a[j], m, 64);
  }

  if (slot == 0) {
    const float* bi = bias + b * DIM + fl * 8;
#pragma unroll
    for (int j = 0; j < 8; ++j) {
      a[j] += bi[j];
      if (relu) a[j] = fmaxf(a[j], 0.f);
    }
    union { bf16 h[8]; uint4 u4; } pk;
#pragma unroll
    for (int j = 0; j < 8; ++j) pk.h[j] = (bf16)a[j];
    *(uint4*)(out + (size_t)b * outBr + (size_t)n * ldOut + fl * 8) = pk.u4;
  }
}

// ---------------- bf16 MFMA GEMM ----------------
// C[MPAD][ldC](bf16) = A[MPAD][ldA](bf16) @ B^T[BN][K](bf16), single N-tile (N==BN)
template <int BN, bool BR>
__global__ void __launch_bounds__(256) k_gemm(
    const bf16* __restrict__ A, const bf16* __restrict__ B, bf16* __restrict__ C,
    const float* __restrict__ bias, int K, int ldA, int ldC,
    size_t sA, size_t sB, size_t sC) {
  constexpr int WN = BN / 2;
  constexpr int NFR = WN / 16;
  constexpr int BL = BN / 32;                 // B-stage loads per wave
  __shared__ __align__(16) unsigned char sa[128 * 128];   // 128 rows x 128B (64 bf16)
  __shared__ __align__(16) unsigned char sb[BN * 128];
  int tid = threadIdx.x;
  int lane = tid & 63;
  int wid = tid >> 6;
  int wm = wid & 1, wn = wid >> 1;
  const bf16* Ab = A + sA * blockIdx.z;
  const bf16* Bb = B + sB * blockIdx.z;
  bf16* Cb = C + sC * blockIdx.z;
  int gm0 = blockIdx.x * 128;

  f32x4 acc[4][NFR];
#pragma unroll
  for (int i = 0; i < 4; ++i)
#pragma unroll
    for (int j = 0; j < NFR; ++j) acc[i][j] = (f32x4){0.f, 0.f, 0.f, 0.f};

  for (int kt = 0; kt < K; kt += 64) {
#pragma unroll
    for (int i = 0; i < 4; ++i) {
      int lb = (wid * 4 + i) * 1024 + lane * 16;
      int r = lb >> 7;
      int c = (lb >> 4) & 7;
      gload16(Ab + (size_t)(gm0 + r) * ldA + kt + ((c ^ (r & 7)) << 3),
              &sa[(wid * 4 + i) * 1024]);
    }
#pragma unroll
    for (int i = 0; i < BL; ++i) {
      int lb = (wid * BL + i) * 1024 + lane * 16;
      int r = lb >> 7;
      int c = (lb >> 4) & 7;
      gload16(Bb + (size_t)r * K + kt + ((c ^ (r & 7)) << 3),
              &sb[(wid * BL + i) * 1024]);
    }
    __syncthreads();
#pragma unroll
    for (int kk = 0; kk < 2; ++kk) {
      bf16x8 ar[4], br[NFR];
#pragma unroll
      for (int mi = 0; mi < 4; ++mi) {
        int r = wm * 64 + mi * 16 + (lane & 15);
        int c = (kk * 4 + (lane >> 4)) ^ (r & 7);
        ar[mi] = *(const bf16x8*)&sa[r * 128 + c * 16];
      }
#pragma unroll
      for (int ni = 0; ni < NFR; ++ni) {
        int r = wn * WN + ni * 16 + (lane & 15);
        int c = (kk * 4 + (lane >> 4)) ^ (r & 7);
        br[ni] = *(const bf16x8*)&sb[r * 128 + c * 16];
      }
#pragma unroll
      for (int mi = 0; mi < 4; ++mi)
#pragma unroll
        for (int ni = 0; ni < NFR; ++ni)
          acc[mi][ni] = __builtin_amdgcn_mfma_f32_16x16x32_bf16(br[ni], ar[mi], acc[mi][ni], 0, 0, 0);
    }
    __syncthreads();
  }

#pragma unroll
  for (int mi = 0; mi < 4; ++mi) {
    int m = gm0 + wm * 64 + mi * 16 + (lane & 15);
#pragma unroll
    for (int ni = 0; ni < NFR; ++ni) {
      int n0 = wn * WN + ni * 16 + ((lane >> 4) << 2);
      f32x4 v = acc[mi][ni];
      if (BR) {
        const f32x4 bv = *(const f32x4*)&bias[n0];
        v[0] = fmaxf(v[0] + bv[0], 0.f);
        v[1] = fmaxf(v[1] + bv[1], 0.f);
        v[2] = fmaxf(v[2] + bv[2], 0.f);
        v[3] = fmaxf(v[3] + bv[3], 0.f);
      }
      uint2 st;
      st.x = packbf2(v[0], v[1]);
      st.y = packbf2(v[2], v[3]);
      *(uint2*)(Cb + (size_t)m * ldC + n0) = st;
    }
  }
}

// ---------------- dense heads ----------------
__global__ void k_head(const bf16* __restrict__ X, int ldX,
                       const float* __restrict__ W, const float* __restrict__ bias,
                       float* __restrict__ out) {
  int idx = blockIdx.x * 256 + threadIdx.x;
  if (idx >= NN * 40) return;
  int n = idx / 40, c = idx - n * 40;
  const bf16* xr = X + (size_t)n * ldX;
  float acc = bias[c];
#pragma unroll
  for (int d2 = 0; d2 < 32; ++d2) {
    union { uint32_t u; bf16 h[2]; } cv;
    cv.u = *(const uint32_t*)(xr + d2 * 2);
    acc = fmaf(fmaxf((float)cv.h[0], 0.f), W[(d2 * 2) * 40 + c], acc);
    acc = fmaf(fmaxf((float)cv.h[1], 0.f), W[(d2 * 2 + 1) * 40 + c], acc);
  }
  out[idx] = acc;
}

extern "C" void kernel_launch(void* const* d_in, const int* in_sizes, int n_in,
                              void* d_out, int out_size, void* d_ws, size_t ws_size,
                              hipStream_t stream) {
  (void)in_sizes; (void)n_in; (void)out_size; (void)ws_size;
  const float* x   = (const float*)d_in[0];
  const int*   src = (const int*)d_in[1];
  const int*   dst = (const int*)d_in[2];
  const float* val = (const float*)d_in[3];
  const float* Wa  = (const float*)d_in[4];
  const float* ba  = (const float*)d_in[5];
  const float* Wb  = (const float*)d_in[6];
  const float* bb  = (const float*)d_in[7];
  const float* Wc  = (const float*)d_in[8];
  const float* bc  = (const float*)d_in[9];
  const float* dW  = (const float*)d_in[10];
  const float* db  = (const float*)d_in[11];
  const float* e1W = (const float*)d_in[12];
  const float* e1b = (const float*)d_in[13];
  const float* e2W = (const float*)d_in[14];
  const float* e2b = (const float*)d_in[15];
  const float* e3W = (const float*)d_in[16];
  const float* e3b = (const float*)d_in[17];
  float* out = (float*)d_out;

  uint8_t* ws = (uint8_t*)d_ws;
  size_t off = 0;
  auto carve = [&](size_t sz) -> void* {
    void* p = ws + off;
    off = (off + sz + 255) & ~(size_t)255;
    return p;
  };

  bf16* xbf   = (bf16*)carve((size_t)MPAD * KP * 2);       // 51.2 MB (aliased later by e-bufs)
  bf16* WaT   = (bf16*)carve((size_t)4 * 128 * KP * 2);
  bf16* WbT   = (bf16*)carve((size_t)4 * 128 * 128 * 2);
  bf16* WcT   = (bf16*)carve((size_t)4 * 64 * 128 * 2);
  bf16* e1WT  = (bf16*)carve((size_t)128 * 256 * 2);
  bf16* e2WT  = (bf16*)carve((size_t)128 * 128 * 2);
  bf16* e3WT  = (bf16*)carve((size_t)64 * 128 * 2);
  bf16* bufS  = (bf16*)carve((size_t)4 * MPAD * 128 * 2);  // support1/2/3 (+sort staging alias)
  bf16* bufH  = (bf16*)carve((size_t)4 * MPAD * 128 * 2);  // h1/h2, then xbcat [MPAD][256]
  int*  bcnt  = (int*)carve((size_t)4 * NBK * 4);
  int*  gfill = (int*)carve((size_t)4 * NBK * 4);
  int*  bases = (int*)carve((size_t)4 * (NBK + 1) * 4);
  int*  offs  = (int*)carve((size_t)4 * (NN + 1) * 4);
  int2* edata = (int2*)carve((size_t)4 * NE * 8);
  // sort staging aliases bufS (dead until GEMM1; sort completes before GEMM1 in-stream)
  int4* staging = (int4*)bufS;
  // e-bufs alias xbf (dead after GEMM1)
  bf16* e1buf = xbf;
  bf16* e2buf = xbf + (size_t)MPAD * 128;
  bf16* e3buf = xbf + (size_t)2 * MPAD * 128;

  hipMemsetAsync(bcnt, 0, (size_t)4 * NBK * 4, stream);

  // converts
  k_conv_x  <<<(NN * KP + 255) / 256, 256, 0, stream>>>(x, xbf);
  k_conv_waT<<<(4 * 128 * KP + 255) / 256, 256, 0, stream>>>(Wa, WaT);
  k_conv_wT <<<dim3((128 * 128 + 255) / 256, 4), 256, 0, stream>>>(Wb, WbT, 128, 128);
  k_conv_wT <<<dim3((128 * 64 + 255) / 256, 4), 256, 0, stream>>>(Wc, WcT, 128, 64);
  k_conv_wT <<<dim3((256 * 128 + 255) / 256, 1), 256, 0, stream>>>(e1W, e1WT, 256, 128);
  k_conv_wT <<<dim3((128 * 128 + 255) / 256, 1), 256, 0, stream>>>(e2W, e2WT, 128, 128);
  k_conv_wT <<<dim3((128 * 64 + 255) / 256, 1), 256, 0, stream>>>(e3W, e3WT, 128, 64);

  // CSR build (binned two-level counting sort)
  const int EB = (NE + 4095) / 4096;   // 98
  k_bhist<<<dim3(EB, 1, 4), 256, 0, stream>>>(dst, bcnt);
  k_bscan<<<1, 256, 0, stream>>>(bcnt, bases, gfill, offs);
  k_bin  <<<dim3(EB, 1, 4), 256, 0, stream>>>(src, dst, val, gfill, staging);
  k_fine <<<dim3(NBK, 1, 4), 256, 0, stream>>>(staging, bases, offs, edata);

  const dim3 gemmGrid4(MPAD / 128, 1, 4);
  const dim3 gemmGrid1(MPAD / 128, 1, 1);

  // layer 1: support1 = xbf @ WaT^T ; h1 = relu(spmm + ba)
  k_gemm<128, false><<<gemmGrid4, 256, 0, stream>>>(xbf, WaT, bufS, nullptr, KP, KP, 128,
                                                    0, (size_t)128 * KP, (size_t)MPAD * 128);
  k_spmm<128><<<dim3((NN + 3) / 4, 1, 4), 256, 0, stream>>>(bufS, offs, edata, ba, bufH,
                                                            128, (long long)MPAD * 128, 1);
  // layer 2
  k_gemm<128, false><<<gemmGrid4, 256, 0, stream>>>(bufH, WbT, bufS, nullptr, 128, 128, 128,
                                                    (size_t)MPAD * 128, (size_t)128 * 128, (size_t)MPAD * 128);
  k_spmm<128><<<dim3((NN + 3) / 4, 1, 4), 256, 0, stream>>>(bufS, offs, edata, bb, bufH,
                                                            128, (long long)MPAD * 128, 1);
  // layer 3 (no relu); spmm3 writes cat layout [n][branch*64+d] into bufH
  k_gemm<64, false><<<gemmGrid4, 256, 0, stream>>>(bufH, WcT, bufS, nullptr, 128, 128, 64,
                                                   (size_t)MPAD * 128, (size_t)64 * 128, (size_t)MPAD * 64);
  k_spmm<64><<<dim3((NN + 3) / 4, 1, 4), 256, 0, stream>>>(bufS, offs, edata, bc, bufH,
                                                           256, 64, 0);
  // per-branch dense heads on relu(xb)
  for (int k = 0; k < 4; ++k)
    k_head<<<(NN * 40 + 255) / 256, 256, 0, stream>>>(bufH + k * 64, 256,
                                                      dW + (size_t)k * 64 * 40, db + k * 40,
                                                      out + (size_t)k * NN * 40);
  // ensemble MLP on cat (bufH)
  k_gemm<128, true><<<gemmGrid1, 256, 0, stream>>>(bufH, e1WT, e1buf, e1b, 256, 256, 128, 0, 0, 0);
  k_gemm<128, true><<<gemmGrid1, 256, 0, stream>>>(e1buf, e2WT, e2buf, e2b, 128, 128, 128, 0, 0, 0);
  k_gemm<64,  true><<<gemmGrid1, 256, 0, stream>>>(e2buf, e3WT, e3buf, e3b, 128, 128, 64, 0, 0, 0);
  k_head<<<(NN * 40 + 255) / 256, 256, 0, stream>>>(e3buf, 64, dW + (size_t)4 * 64 * 40, db + 4 * 40,
                                                    out + (size_t)4 * NN * 40);
}